// Round 16
// baseline (183.336 us; speedup 1.0000x reference)
//
#include <hip/hip_runtime.h>
#include <hip/hip_bf16.h>

// out[m,b,:] = kv[m,b,:] @ W + bo + query[b,:],  W = (Wo@Wv) row o, col d
// (softmax over size-1 axis == 1 -> ones; q/k/Wq/Wk dead). f32 output.
// K1: Cw = Wo@Wv, MFMA bf16, 64x64 tiles, 256 blocks (~3us, proven r9).
// K2: r15 (BK=64, both-tiles XOR swizzle, 2-barrier, 4096 blocks) with the
//     A path upgraded: reg-staged to LDS as BF16 (halves A LDS bytes+reads,
//     cvt moves out of compute) + A-reg prefetch of kt+1 under compute(kt).
//     LDS 24 KB. Per-CU LDS pipe was the r15 critical path (~95us of 167).

typedef __attribute__((ext_vector_type(4))) float f32x4;
typedef __attribute__((ext_vector_type(8))) short short8;

#define D_MODEL 1024
#define BATCH   4096
#define M_ROWS  32768   // 8 * 4096

__device__ __forceinline__ short f2bf(float f) {
    union { float f; unsigned u; } x; x.f = f;
    unsigned r = (x.u + 0x7fffu + ((x.u >> 16) & 1u)) >> 16;   // RNE
    return (short)r;
}

__device__ __forceinline__ unsigned bfpk(float lo, float hi) {
    __hip_bfloat162 h = __float22bfloat162_rn(make_float2(lo, hi));  // v_cvt_pk_bf16_f32
    unsigned u; __builtin_memcpy(&u, &h, 4); return u;
}

__device__ __forceinline__ short8 cvt8(float4 a, float4 b) {
    union { unsigned u[4]; short8 s; } r;
    r.u[0] = bfpk(a.x, a.y);
    r.u[1] = bfpk(a.z, a.w);
    r.u[2] = bfpk(b.x, b.y);
    r.u[3] = bfpk(b.z, b.w);
    return r.s;
}

// ---------------- Kernel 1: fuse weights Cw = Wo @ Wv (bf16, MFMA, 64x64) ----------------
__global__ __launch_bounds__(256) void fuse_w_kernel(
        const float* __restrict__ Wo, const float* __restrict__ Wv,
        short* __restrict__ Cw) {
    __shared__ __align__(16) short Ash[64][32];   // Wo tile  [o][e]
    __shared__ __align__(16) short Bsh[64][32];   // Wv tile transposed: [d][e]
    const int t = threadIdx.x;
    const int lane = t & 63;
    const int w = t >> 6;
    const int wr = w >> 1, wc = w & 1;
    const int brow = blockIdx.y * 64;   // o
    const int bcol = blockIdx.x * 64;   // d

    f32x4 acc[2][2];
#pragma unroll
    for (int m = 0; m < 2; ++m)
#pragma unroll
        for (int n = 0; n < 2; ++n) acc[m][n] = (f32x4)(0.0f);

    for (int kt = 0; kt < 32; ++kt) {
        const float* ga = Wo + (size_t)(brow + (t >> 2)) * D_MODEL + kt * 32 + (t & 3) * 8;
        float4 a0 = *(const float4*)ga;
        float4 a1 = *(const float4*)(ga + 4);
        float4 bv[2];
#pragma unroll
        for (int j = 0; j < 2; ++j) {
            int lin = j * 256 + t;
            int e = lin >> 4, c4 = lin & 15;
            bv[j] = *(const float4*)(Wv + (size_t)(kt * 32 + e) * D_MODEL + bcol + c4 * 4);
        }
        *reinterpret_cast<short8*>(&Ash[t >> 2][(t & 3) * 8]) = cvt8(a0, a1);
#pragma unroll
        for (int j = 0; j < 2; ++j) {
            int lin = j * 256 + t;
            int e = lin >> 4, c4 = lin & 15;
            int d = c4 * 4;
            Bsh[d + 0][e] = f2bf(bv[j].x);
            Bsh[d + 1][e] = f2bf(bv[j].y);
            Bsh[d + 2][e] = f2bf(bv[j].z);
            Bsh[d + 3][e] = f2bf(bv[j].w);
        }
        __syncthreads();
        {
            const int r = lane & 15, q = lane >> 4;
            short8 af[2], bfr[2];
#pragma unroll
            for (int m = 0; m < 2; ++m)
                af[m] = *reinterpret_cast<const short8*>(&Ash[wr * 32 + m * 16 + r][q * 8]);
#pragma unroll
            for (int n = 0; n < 2; ++n)
                bfr[n] = *reinterpret_cast<const short8*>(&Bsh[wc * 32 + n * 16 + r][q * 8]);
#pragma unroll
            for (int m = 0; m < 2; ++m)
#pragma unroll
                for (int n = 0; n < 2; ++n)
                    acc[m][n] = __builtin_amdgcn_mfma_f32_16x16x32_bf16(
                        af[m], bfr[n], acc[m][n], 0, 0, 0);
        }
        __syncthreads();
    }

    const int r = lane & 15, q = lane >> 4;
#pragma unroll
    for (int m = 0; m < 2; ++m)
#pragma unroll
        for (int n = 0; n < 2; ++n)
#pragma unroll
            for (int j = 0; j < 4; ++j) {
                int o = brow + wr * 32 + m * 16 + q * 4 + j;     // C/D: row=(l>>4)*4+j
                int d = bcol + wc * 32 + n * 16 + r;             //      col=l&15
                Cw[(size_t)o * D_MODEL + d] = f2bf(acc[m][n][j]);
            }
}

// ---------------- Kernel 2: out = kv @ Cw.T + bo + query — BK=64, bf16 LDS both, 2-barrier ----------------
__global__ __launch_bounds__(256, 4) void attn_gemm_kernel(
        const float* __restrict__ kv, const float* __restrict__ query,
        const short* __restrict__ Cw, const float* __restrict__ bo,
        float* __restrict__ out) {
    // A: 64 rows x 64 bf16 (128B row = 8 chunks of 16B), XOR-swizzled, 8 KB.
    //    Reg-staged: global f32 -> cvt -> ds_write (per-lane scatter OK).
    // B: 128 rows x 64 bf16 (8 chunks), XOR-swizzled via glds SOURCE, 16 KB.
    // Both read as chunk c at position c^(row&7).
    __shared__ __align__(16) short Abs[64][64];    // 8 KB
    __shared__ __align__(16) short Bsh[128][64];   // 16 KB
    const int t = threadIdx.x;
    const int lane = t & 63;
    const int w = t >> 6;
    const int wr = w >> 1, wc = w & 1;
    const int r = lane & 15, q = lane >> 4;

    // XCD swizzle: XCD = L % 8; 8 o-tiles of one row-tile share an XCD ->
    // kv L2-reused 8x (proven r8: FETCH 574->141 MB).
    const int L = blockIdx.x;
    const int x = L & 7, j5 = L >> 3;
    const int bx = j5 & 7;                   // o-tile (0..7)
    const int rt = (j5 >> 3) * 8 + x;        // row-tile (0..511)
    const int brow = rt * 64;

    f32x4 acc[2][4];
#pragma unroll
    for (int m = 0; m < 2; ++m)
#pragma unroll
        for (int n = 0; n < 4; ++n) acc[m][n] = (f32x4)(0.0f);

    // A-reg staging: thread t owns row t>>2, f32 elements 16*(t&3)..+15
    // (= bf16 chunks 2*(t&3), 2*(t&3)+1).
    const int arow = t >> 2;
    const float* abase = kv + (size_t)(brow + arow) * D_MODEL + 16 * (t & 3);
    float4 ar[4];

    auto load_a = [&](int kt) {
        const float* g = abase + kt * 64;
        ar[0] = *(const float4*)(g + 0);
        ar[1] = *(const float4*)(g + 4);
        ar[2] = *(const float4*)(g + 8);
        ar[3] = *(const float4*)(g + 12);
    };
    auto write_a = [&]() {
        int c0 = (2 * (t & 3)) ^ (arow & 7);
        int c1 = (2 * (t & 3) + 1) ^ (arow & 7);
        *reinterpret_cast<short8*>(&Abs[arow][c0 * 8]) = cvt8(ar[0], ar[1]);
        *reinterpret_cast<short8*>(&Abs[arow][c1 * 8]) = cvt8(ar[2], ar[3]);
    };
    auto glds_b = [&](int kt) {
        // B: 16 KB = 4 glds issues. chunk=i*256+t; row=chunk>>3, d=chunk&7;
        // source chunk cs = d^(row&7) (both-sides swizzle, rule #21).
#pragma unroll
        for (int i = 0; i < 4; ++i) {
            int chunk = i * 256 + t;
            int rl = chunk >> 3, d = chunk & 7;
            int cs = d ^ (rl & 7);
            const short* g = Cw + (size_t)(bx * 128 + rl) * D_MODEL + kt * 64 + cs * 8;
            __builtin_amdgcn_global_load_lds(
                (const __attribute__((address_space(1))) void*)g,
                (__attribute__((address_space(3))) void*)
                    ((char*)&Bsh[0][0] + i * 4096 + w * 1024),
                16, 0, 0);
        }
    };
    auto compute = [&]() {
#pragma unroll
        for (int s = 0; s < 2; ++s) {
            short8 af[2], bfr[4];
#pragma unroll
            for (int m = 0; m < 2; ++m) {
                int row = wr * 32 + m * 16 + r;
                int c = (s * 4 + q) ^ (row & 7);
                af[m] = *reinterpret_cast<const short8*>(&Abs[row][c * 8]);
            }
#pragma unroll
            for (int n = 0; n < 4; ++n) {
                int row = wc * 64 + n * 16 + r;
                int c = (s * 4 + q) ^ (row & 7);
                bfr[n] = *reinterpret_cast<const short8*>(&Bsh[row][c * 8]);
            }
#pragma unroll
            for (int m = 0; m < 2; ++m)
#pragma unroll
                for (int n = 0; n < 4; ++n)
                    acc[m][n] = __builtin_amdgcn_mfma_f32_16x16x32_bf16(
                        af[m], bfr[n], acc[m][n], 0, 0, 0);
        }
    };

    load_a(0);
    for (int kt = 0; kt < 16; ++kt) {
        glds_b(kt);                    // 4 glds in flight
        write_a();                     // waits only the A-reg loads; cvt here
        __syncthreads();               // implicit full drain: LDS valid
        if (kt < 15) load_a(kt + 1);   // prefetch next A-regs under compute
        compute();
        __syncthreads();               // LDS reuse fence (drains prefetch too)
    }

    // epilogue: + bo + query residual, f32 store
#pragma unroll
    for (int n = 0; n < 4; ++n) {
        int o = bx * 128 + wc * 64 + n * 16 + r;
        float bov = bo[o];
#pragma unroll
        for (int m = 0; m < 2; ++m) {
            int gb = brow + wr * 32 + m * 16 + q * 4;
#pragma unroll
            for (int j = 0; j < 4; ++j) {
                int grow = gb + j;
                out[(size_t)grow * D_MODEL + o] =
                    acc[m][n][j] + bov +
                    query[(size_t)(grow & (BATCH - 1)) * D_MODEL + o];
            }
        }
    }
}

extern "C" void kernel_launch(void* const* d_in, const int* in_sizes, int n_in,
                              void* d_out, int out_size, void* d_ws, size_t ws_size,
                              hipStream_t stream) {
    // Robust input classification by element count (falls back to dict order):
    int kv_i = 1, q_i = 0, bo_i = 6;
    int w_i[4] = {2, 3, 4, 5};
    int nw = 0;
    for (int i = 0; i < n_in; ++i) {
        long s = in_sizes[i];
        if (s == 33554432) kv_i = i;
        else if (s == 4194304) q_i = i;
        else if (s == 1024) bo_i = i;
        else if (s == 1048576 && nw < 4) w_i[nw++] = i;
    }
    const float* query = (const float*)d_in[q_i];
    const float* kv    = (const float*)d_in[kv_i];
    const float* Wv    = (const float*)d_in[w_i[2]];
    const float* Wo    = (const float*)d_in[w_i[3]];
    const float* bo    = (const float*)d_in[bo_i];
    short* Cw  = (short*)d_ws;              // 1024*1024 bf16 = 2 MB
    float* out = (float*)d_out;             // f32 output

    fuse_w_kernel<<<dim3(16, 16), dim3(256), 0, stream>>>(Wo, Wv, Cw);
    attn_gemm_kernel<<<dim3(4096), dim3(256), 0, stream>>>(kv, query, Cw, bo, out);
}